// Round 1
// baseline (1571.426 us; speedup 1.0000x reference)
//
#include <hip/hip_runtime.h>
#include <math.h>

#define CD 512
#define NNODE 64

// ---------------- weight transpose: Wt[k][c] = W[c][k] ----------------
__global__ void transpose_k(const float* __restrict__ W0, const float* __restrict__ W1,
                            const float* __restrict__ W2, const float* __restrict__ W3,
                            const float* __restrict__ W4, const float* __restrict__ W5,
                            const float* __restrict__ W6, const float* __restrict__ W7,
                            const float* __restrict__ W8, const float* __restrict__ W9,
                            float* __restrict__ wt)
{
    __shared__ float tl[32][33];
    const float* srcs[10] = {W0,W1,W2,W3,W4,W5,W6,W7,W8,W9};
    const float* W = srcs[blockIdx.z];
    float* out = wt + (size_t)blockIdx.z * (CD * CD);
    int kb = blockIdx.x * 32, cb = blockIdx.y * 32;
    int tx = threadIdx.x, ty = threadIdx.y;   // (32, 8)
    #pragma unroll
    for (int yy = 0; yy < 32; yy += 8)
        tl[ty + yy][tx] = W[(size_t)(cb + ty + yy) * CD + kb + tx];
    __syncthreads();
    #pragma unroll
    for (int yy = 0; yy < 32; yy += 8)
        out[(size_t)(kb + ty + yy) * CD + cb + tx] = tl[tx][ty + yy];
}

// ---------------- 4 small matmuls: O[z] = A(1024x512) @ Wt[z] ----------------
__global__ __launch_bounds__(512, 2) void gemm4(
    const float* __restrict__ A,
    const float* __restrict__ Wt0, const float* __restrict__ Wt1,
    const float* __restrict__ Wt2, const float* __restrict__ Wt3,
    float* __restrict__ O0, float* __restrict__ O1,
    float* __restrict__ O2, float* __restrict__ O3)
{
    __shared__ __align__(16) float ta[NNODE * CD];     // 128 KB
    __shared__ __align__(16) float panel[8 * 128];     // 4 KB
    const float* Wtb[4] = {Wt0, Wt1, Wt2, Wt3};
    float* Ob[4] = {O0, O1, O2, O3};
    const float* Wt = Wtb[blockIdx.z];
    float* out = Ob[blockIdx.z];
    const int rb = blockIdx.x * 64;      // row block (of 1024 rows)
    const int cs = blockIdx.y * 128;     // c slice
    const int t = threadIdx.x;
    const int lane = t & 63;
    const int wv = t >> 6;               // 0..7

    const float* asrc = A + (size_t)rb * CD;
    #pragma unroll
    for (int ii = 0; ii < 16; ++ii) {
        int flat = ii * 2048 + t * 4;
        *(float4*)(ta + flat) = *(const float4*)(asrc + flat);
    }
    __syncthreads();

    float acc[8][2];
    #pragma unroll
    for (int jj = 0; jj < 8; ++jj) { acc[jj][0] = 0.f; acc[jj][1] = 0.f; }
    const int j0 = wv * 8;

    for (int k0 = 0; k0 < CD; k0 += 8) {
        {
            int kk = t >> 6;
            int cc = t & 63;
            const float* src = Wt + (size_t)(k0 + kk) * CD + cs + cc;
            panel[kk * 128 + cc]      = src[0];
            panel[kk * 128 + cc + 64] = src[64];
        }
        __syncthreads();
        float pv[8][2];
        #pragma unroll
        for (int kk = 0; kk < 8; ++kk) {
            pv[kk][0] = panel[kk * 128 + lane];
            pv[kk][1] = panel[kk * 128 + lane + 64];
        }
        __syncthreads();
        #pragma unroll
        for (int jj = 0; jj < 8; ++jj) {
            const float* tr = ta + (j0 + jj) * CD + k0;
            float4 a0 = *(const float4*)tr;
            float4 a1 = *(const float4*)(tr + 4);
            float av[8] = {a0.x, a0.y, a0.z, a0.w, a1.x, a1.y, a1.z, a1.w};
            #pragma unroll
            for (int kk = 0; kk < 8; ++kk) {
                acc[jj][0] = fmaf(av[kk], pv[kk][0], acc[jj][0]);
                acc[jj][1] = fmaf(av[kk], pv[kk][1], acc[jj][1]);
            }
        }
    }
    #pragma unroll
    for (int jj = 0; jj < 8; ++jj) {
        size_t ro = (size_t)(rb + j0 + jj) * CD + cs;
        out[ro + lane]      = acc[jj][0];
        out[ro + lane + 64] = acc[jj][1];
    }
}

// ---------------- fused edge kernel: one block per (b,i) ----------------
// e_lin = tile @ WEt; m = e_lin + Vix[i] + Vjx[j]; env = tile + relu(LN(m));
// write env; tile <- exp(sigmoid(env)); agg = (sum_j w*Ujx) / (sum_j w) / 64
__global__ __launch_bounds__(512, 2) void edge_kernel(
    const float* __restrict__ ein,
    float* __restrict__ eout,
    const float* __restrict__ Vix,
    const float* __restrict__ Vjx,
    const float* __restrict__ Ujx,
    const float* __restrict__ WEt,
    const float* __restrict__ ge, const float* __restrict__ be,
    float* __restrict__ agg)
{
    __shared__ __align__(16) float tile[NNODE * CD];   // 128 KB
    __shared__ __align__(16) float panel[8 * CD];      // 16 KB
    const int bi = blockIdx.x;           // b*64 + i
    const int t = threadIdx.x;           // 0..511
    const int lane = t & 63;
    const int wv = t >> 6;               // 0..7
    const int brow = (bi >> 6) << 6;     // b*64

    const float* esrc = ein + (size_t)bi * (NNODE * CD);
    #pragma unroll
    for (int ii = 0; ii < 16; ++ii) {
        int flat = ii * 2048 + t * 4;
        *(float4*)(tile + flat) = *(const float4*)(esrc + flat);
    }
    __syncthreads();

    float acc[8][8];
    #pragma unroll
    for (int jj = 0; jj < 8; ++jj)
        #pragma unroll
        for (int u = 0; u < 8; ++u) acc[jj][u] = 0.f;
    const int j0 = wv * 8;

    for (int k0 = 0; k0 < CD; k0 += 8) {
        {   // stage WEt panel: 8 k-rows x 512 c (read once per block total)
            int kk = t >> 6;
            int cc = t & 63;
            const float* src = WEt + (size_t)(k0 + kk) * CD + cc;
            float* dst = panel + kk * CD + cc;
            #pragma unroll
            for (int u = 0; u < 8; ++u) dst[u * 64] = src[u * 64];
        }
        __syncthreads();
        float pv[8][8];
        #pragma unroll
        for (int kk = 0; kk < 8; ++kk)
            #pragma unroll
            for (int u = 0; u < 8; ++u)
                pv[kk][u] = panel[kk * CD + lane + u * 64];
        __syncthreads();
        #pragma unroll
        for (int jj = 0; jj < 8; ++jj) {
            const float* tr = tile + (j0 + jj) * CD + k0;   // wave-broadcast reads
            float4 a0 = *(const float4*)tr;
            float4 a1 = *(const float4*)(tr + 4);
            float av[8] = {a0.x, a0.y, a0.z, a0.w, a1.x, a1.y, a1.z, a1.w};
            #pragma unroll
            for (int kk = 0; kk < 8; ++kk)
                #pragma unroll
                for (int u = 0; u < 8; ++u)
                    acc[jj][u] = fmaf(av[kk], pv[kk][u], acc[jj][u]);
        }
    }

    // ---- LN over c per j-row (each wave owns its 8 rows; row-local tile writes) ----
    float vix[8], gev[8], bev[8];
    #pragma unroll
    for (int u = 0; u < 8; ++u) {
        int c = lane + u * 64;
        vix[u] = Vix[(size_t)bi * CD + c];
        gev[u] = ge[c];
        bev[u] = be[c];
    }
    #pragma unroll
    for (int jj = 0; jj < 8; ++jj) {
        int j = j0 + jj;
        const float* vjr = Vjx + (size_t)(brow + j) * CD;
        float m[8]; float s1 = 0.f, s2 = 0.f;
        #pragma unroll
        for (int u = 0; u < 8; ++u) {
            float mv = acc[jj][u] + vix[u] + vjr[lane + u * 64];
            m[u] = mv; s1 += mv; s2 += mv * mv;
        }
        #pragma unroll
        for (int off = 32; off > 0; off >>= 1) {
            s1 += __shfl_xor(s1, off, 64);
            s2 += __shfl_xor(s2, off, 64);
        }
        float mean = s1 * (1.f / 512.f);
        float var  = s2 * (1.f / 512.f) - mean * mean;
        float rs   = rsqrtf(var + 1e-5f);
        float* trow = tile + j * CD;
        float* erow = eout + ((size_t)bi * NNODE + j) * CD;
        #pragma unroll
        for (int u = 0; u < 8; ++u) {
            int c = lane + u * 64;
            float ln  = (m[u] - mean) * rs * gev[u] + bev[u];
            float env = trow[c] + fmaxf(ln, 0.f);
            erow[c] = env;
            float sg = 1.f / (1.f + __expf(-env));
            trow[c] = __expf(sg);     // overwrite tile with softmax numerator
        }
    }
    __syncthreads();

    // ---- softmax-over-j reduction + aggregation: thread t owns channel c=t ----
    {
        int c = t;
        const float* uj = Ujx + (size_t)brow * CD + c;
        float den = 0.f, num = 0.f;
        #pragma unroll 8
        for (int j = 0; j < NNODE; ++j) {
            float wj = tile[j * CD + c];
            float uv = uj[(size_t)j * CD];
            den += wj;
            num = fmaf(wj, uv, num);
        }
        agg[(size_t)bi * CD + c] = num / (den * (float)NNODE);
    }
}

// ---------------- x update: x = relu(res + LN(XU + agg)) ----------------
__global__ __launch_bounds__(256) void xupd_kernel(
    const float* __restrict__ res,
    const float* __restrict__ XU,
    const float* __restrict__ aggp,
    const float* __restrict__ gv, const float* __restrict__ bv,
    float* __restrict__ xout)
{
    int r = blockIdx.x * 4 + (threadIdx.x >> 6);   // one wave per row
    int lane = threadIdx.x & 63;
    const float* xu = XU + (size_t)r * CD;
    const float* ag = aggp + (size_t)r * CD;
    float y[8]; float s1 = 0.f, s2 = 0.f;
    #pragma unroll
    for (int u = 0; u < 8; ++u) {
        int c = lane + u * 64;
        float v = xu[c] + ag[c];
        y[u] = v; s1 += v; s2 += v * v;
    }
    #pragma unroll
    for (int off = 32; off > 0; off >>= 1) {
        s1 += __shfl_xor(s1, off, 64);
        s2 += __shfl_xor(s2, off, 64);
    }
    float mean = s1 * (1.f / 512.f);
    float var  = s2 * (1.f / 512.f) - mean * mean;
    float rs   = rsqrtf(var + 1e-5f);
    const float* rr = res + (size_t)r * CD;
    float* xo = xout + (size_t)r * CD;
    #pragma unroll
    for (int u = 0; u < 8; ++u) {
        int c = lane + u * 64;
        float ln = (y[u] - mean) * rs * gv[c] + bv[c];
        xo[c] = fmaxf(rr[c] + ln, 0.f);
    }
}

extern "C" void kernel_launch(void* const* d_in, const int* in_sizes, int n_in,
                              void* d_out, int out_size, void* d_ws, size_t ws_size,
                              hipStream_t stream)
{
    const float* x    = (const float*)d_in[0];
    const float* edge = (const float*)d_in[1];
    const float* W[10];
    for (int i = 0; i < 10; ++i) W[i] = (const float*)d_in[2 + i];
    // dict order: ge1, gv1, ge2, gv2, be1, bv1, be2, bv2
    const float* ge1 = (const float*)d_in[12];
    const float* gv1 = (const float*)d_in[13];
    const float* ge2 = (const float*)d_in[14];
    const float* gv2 = (const float*)d_in[15];
    const float* be1 = (const float*)d_in[16];
    const float* bv1 = (const float*)d_in[17];
    const float* be2 = (const float*)d_in[18];
    const float* bv2 = (const float*)d_in[19];

    float* ws  = (float*)d_ws;
    float* Wt  = ws;                          // 10 * 262144 floats
    float* Vix = ws + 10 * 262144;            // each 1024*512
    float* Vjx = Vix + 524288;
    float* Ujx = Vjx + 524288;
    float* XU  = Ujx + 524288;
    float* agg = XU  + 524288;
    float* x1  = agg + 524288;                // total ~23 MB

    float* xout = (float*)d_out;
    float* eint = xout + 524288;              // edge region of d_out (intermediate + final)

    transpose_k<<<dim3(16, 16, 10), dim3(32, 8), 0, stream>>>(
        W[0], W[1], W[2], W[3], W[4], W[5], W[6], W[7], W[8], W[9], Wt);

#define WT(i) (Wt + (size_t)(i) * 262144)
    // names: 0 WA1, 1 WB1, 2 WE1, 3 WU1, 4 WV1, 5 WA2, 6 WB2, 7 WE2, 8 WU2, 9 WV2
    // ---- layer 1 ----
    gemm4<<<dim3(16, 4, 4), 512, 0, stream>>>(x, WT(0), WT(1), WT(4), WT(3),
                                              Vix, Vjx, Ujx, XU);
    edge_kernel<<<1024, 512, 0, stream>>>(edge, eint, Vix, Vjx, Ujx, WT(2), ge1, be1, agg);
    xupd_kernel<<<256, 256, 0, stream>>>(x, XU, agg, gv1, bv1, x1);
    // ---- layer 2 ----
    gemm4<<<dim3(16, 4, 4), 512, 0, stream>>>(x1, WT(5), WT(6), WT(9), WT(8),
                                              Vix, Vjx, Ujx, XU);
    edge_kernel<<<1024, 512, 0, stream>>>(eint, eint, Vix, Vjx, Ujx, WT(7), ge2, be2, agg);
    xupd_kernel<<<256, 256, 0, stream>>>(x1, XU, agg, gv2, bv2, xout);
#undef WT
}

// Round 3
// 591.678 us; speedup vs baseline: 2.6559x; 2.6559x over previous
//
#include <hip/hip_runtime.h>
#include <math.h>

#define CD 512
#define NNODE 64
#define TPAD 520   // bf16 tile row stride: 1040 B = 16B-aligned, conflict-free b128 reads

typedef __attribute__((ext_vector_type(8)))  short bfrag8;   // 8 bf16 (4 VGPRs)
typedef __attribute__((ext_vector_type(4)))  short sv4;
typedef __attribute__((ext_vector_type(4)))  float f32x4;
typedef __attribute__((ext_vector_type(16))) float f32x16;

__device__ __forceinline__ unsigned short f2bf(float f) {
    union { float f; unsigned u; } v; v.f = f;
    unsigned r = (v.u + 0x7fffu + ((v.u >> 16) & 1u)) >> 16;
    return (unsigned short)r;
}
__device__ __forceinline__ float bf2f(unsigned short u) {
    union { unsigned u; float f; } v; v.u = ((unsigned)u) << 16;
    return v.f;
}

// ---------------- pack weights into MFMA-B fragment order ----------------
// 16x16x32: Bp[kt(16)][ct(32)][lane][i(8)] = W[c=ct*16+(l&15)][k=kt*32+(l>>4)*8+i]
__global__ void pack16_k(const float* __restrict__ W0, const float* __restrict__ W1,
                         const float* __restrict__ W2, const float* __restrict__ W3,
                         const float* __restrict__ W4, const float* __restrict__ W5,
                         const float* __restrict__ W6, const float* __restrict__ W7,
                         unsigned short* __restrict__ out)
{
    const float* Ws[8] = {W0,W1,W2,W3,W4,W5,W6,W7};
    int kt = blockIdx.x, ct = blockIdx.y, wi = blockIdx.z, l = threadIdx.x;
    const float* W = Ws[wi];
    int c  = ct * 16 + (l & 15);
    int k0 = kt * 32 + (l >> 4) * 8;
    const float* src = W + (size_t)c * CD + k0;
    unsigned short o[8];
    #pragma unroll
    for (int i = 0; i < 8; ++i) o[i] = f2bf(src[i]);
    unsigned short* dst = out + (size_t)wi * 262144 + ((size_t)(kt * 32 + ct) * 64 + l) * 8;
    *(bfrag8*)dst = *(bfrag8*)o;
}

// 32x32x16: Bp[kt(32)][ct(16)][lane][i(8)] = W[c=ct*32+(l&31)][k=kt*16+(l>>5)*8+i]
__global__ void pack32_k(const float* __restrict__ W0, const float* __restrict__ W1,
                         unsigned short* __restrict__ out)
{
    const float* Ws[2] = {W0,W1};
    int kt = blockIdx.x, ct = blockIdx.y, wi = blockIdx.z, l = threadIdx.x;
    const float* W = Ws[wi];
    int c  = ct * 32 + (l & 31);
    int k0 = kt * 16 + (l >> 5) * 8;
    const float* src = W + (size_t)c * CD + k0;
    unsigned short o[8];
    #pragma unroll
    for (int i = 0; i < 8; ++i) o[i] = f2bf(src[i]);
    unsigned short* dst = out + (size_t)wi * 262144 + ((size_t)(kt * 16 + ct) * 64 + l) * 8;
    *(bfrag8*)dst = *(bfrag8*)o;
}

// ---------------- 4 projections: O[w] = A(1024x512) @ W[w].T, bf16 MFMA ----------------
__global__ __launch_bounds__(256, 2) void gemm4_mfma(
    const float* __restrict__ A, const unsigned short* __restrict__ Bp4,
    float* __restrict__ O0, float* __restrict__ O1,
    float* __restrict__ O2, float* __restrict__ O3)
{
    __shared__ unsigned short atile[16 * TPAD];
    const int rb = blockIdx.x * 16, widx = blockIdx.y;
    float* outs[4] = {O0,O1,O2,O3};
    float* out = outs[widx];
    const unsigned short* Bp = Bp4 + (size_t)widx * 262144;
    const int t = threadIdx.x, l = t & 63, v = t >> 6;

    #pragma unroll
    for (int it = 0; it < 8; ++it) {
        int flat = it * 1024 + t * 4;
        float4 x4 = *(const float4*)(A + (size_t)rb * CD + flat);
        int r = flat >> 9, c = flat & 511;
        sv4 pk; pk.x = (short)f2bf(x4.x); pk.y = (short)f2bf(x4.y);
        pk.z = (short)f2bf(x4.z); pk.w = (short)f2bf(x4.w);
        *(sv4*)(atile + r * TPAD + c) = pk;
    }
    __syncthreads();

    f32x4 acc[8] = {};
    const unsigned short* aptr = atile + (size_t)(l & 15) * TPAD + (l >> 4) * 8;
    const unsigned short* bptr = Bp + (size_t)(v * 8) * 512 + (size_t)l * 8;

    bfrag8 a0, a1, b0[8], b1[8];
    a0 = *(const bfrag8*)aptr;
    #pragma unroll
    for (int tt = 0; tt < 8; ++tt) b0[tt] = *(const bfrag8*)(bptr + tt * 512);
    for (int k2 = 0; k2 < 8; ++k2) {
        int kt1 = 2 * k2 + 1;
        a1 = *(const bfrag8*)(aptr + kt1 * 32);
        #pragma unroll
        for (int tt = 0; tt < 8; ++tt) b1[tt] = *(const bfrag8*)(bptr + (size_t)kt1 * 16384 + tt * 512);
        #pragma unroll
        for (int tt = 0; tt < 8; ++tt)
            acc[tt] = __builtin_amdgcn_mfma_f32_16x16x32_bf16(a0, b0[tt], acc[tt], 0, 0, 0);
        int kt2 = (k2 == 7) ? 15 : (2 * k2 + 2);
        a0 = *(const bfrag8*)(aptr + kt2 * 32);
        #pragma unroll
        for (int tt = 0; tt < 8; ++tt) b0[tt] = *(const bfrag8*)(bptr + (size_t)kt2 * 16384 + tt * 512);
        #pragma unroll
        for (int tt = 0; tt < 8; ++tt)
            acc[tt] = __builtin_amdgcn_mfma_f32_16x16x32_bf16(a1, b1[tt], acc[tt], 0, 0, 0);
    }
    // C layout 16x16: col = lane&15, row = (lane>>4)*4 + reg
    #pragma unroll
    for (int tt = 0; tt < 8; ++tt) {
        int c = (v * 8 + tt) * 16 + (l & 15);
        #pragma unroll
        for (int r = 0; r < 4; ++r) {
            int row = rb + (l >> 4) * 4 + r;
            out[(size_t)row * CD + c] = acc[tt][r];
        }
    }
}

// ---------------- fused edge kernel (2 (b,i) pairs per block, M=128) ----------------
__global__ __launch_bounds__(512, 2) void edge_mfma(
    const float* __restrict__ ein, float* __restrict__ eout,
    const float* __restrict__ Vix, const float* __restrict__ Vjx,
    const float* __restrict__ Ujx, const unsigned short* __restrict__ Bp,
    const float* __restrict__ ge, const float* __restrict__ be,
    float* __restrict__ agg)
{
    __shared__ unsigned short tile[2 * 64 * TPAD];   // 130 KB bf16 edge tile (both pairs)
    __shared__ float sums[128][2][2];                // [row][c-half][s1,s2]

    const int q = blockIdx.x;
    const int b = q >> 5, i0 = q & 31;
    const int bi0 = b * 64 + i0;
    const int t = threadIdx.x, l = t & 63, w = t >> 6;
    const int stripe = w & 3, H = w >> 2, p = stripe >> 1;
    const int brow = b * 64;

    // ---- stage edge (fp32 global -> bf16 LDS): 32768 floats per pair = 16 iters ----
    #pragma unroll
    for (int p2 = 0; p2 < 2; ++p2) {
        const float* src = ein + (size_t)(bi0 + p2 * 32) * 32768;
        unsigned short* dst = tile + p2 * 64 * TPAD;
        #pragma unroll 4
        for (int it = 0; it < 16; ++it) {
            int flat = it * 2048 + t * 4;
            float4 v4 = *(const float4*)(src + flat);
            int r = flat >> 9, c = flat & 511;
            sv4 pk; pk.x = (short)f2bf(v4.x); pk.y = (short)f2bf(v4.y);
            pk.z = (short)f2bf(v4.z); pk.w = (short)f2bf(v4.w);
            *(sv4*)(dst + r * TPAD + c) = pk;
        }
    }
    __syncthreads();

    // ---- K-loop: 32 steps of K=16, zero barriers; B streamed from L2 ----
    f32x16 acc[8] = {};
    const unsigned short* aptr = tile + (size_t)(stripe * 32 + (l & 31)) * TPAD + (l >> 5) * 8;
    const unsigned short* bptr = Bp + (size_t)(H * 8) * 512 + (size_t)l * 8;

    bfrag8 a0, a1, b0[8], b1[8];
    a0 = *(const bfrag8*)aptr;
    #pragma unroll
    for (int tt = 0; tt < 8; ++tt) b0[tt] = *(const bfrag8*)(bptr + tt * 512);
    for (int k2 = 0; k2 < 16; ++k2) {
        int kt1 = 2 * k2 + 1;
        a1 = *(const bfrag8*)(aptr + kt1 * 16);
        #pragma unroll
        for (int tt = 0; tt < 8; ++tt) b1[tt] = *(const bfrag8*)(bptr + (size_t)kt1 * 8192 + tt * 512);
        #pragma unroll
        for (int tt = 0; tt < 8; ++tt)
            acc[tt] = __builtin_amdgcn_mfma_f32_32x32x16_bf16(a0, b0[tt], acc[tt], 0, 0, 0);
        int kt2 = (k2 == 15) ? 31 : (2 * k2 + 2);
        a0 = *(const bfrag8*)(aptr + kt2 * 16);
        #pragma unroll
        for (int tt = 0; tt < 8; ++tt) b0[tt] = *(const bfrag8*)(bptr + (size_t)kt2 * 8192 + tt * 512);
        #pragma unroll
        for (int tt = 0; tt < 8; ++tt)
            acc[tt] = __builtin_amdgcn_mfma_f32_32x32x16_bf16(a1, b1[tt], acc[tt], 0, 0, 0);
    }

    // ---- epilogue: m = acc + vix + vjx; LN stats (32-lane butterfly + LDS halves) ----
    // C layout 32x32: col = lane&31, row = (reg&3) + 8*(reg>>2) + 4*(lane>>5)
    const int cbase = H * 256 + (l & 31);
    const int biP = bi0 + p * 32;
    float vix[8], gev[8], bev[8];
    #pragma unroll
    for (int tt = 0; tt < 8; ++tt) {
        int c = cbase + tt * 32;
        vix[tt] = Vix[(size_t)biP * CD + c];
        gev[tt] = ge[c]; bev[tt] = be[c];
    }
    float s1[16], s2[16];
    #pragma unroll
    for (int r = 0; r < 16; ++r) {
        int rl = (r & 3) + 8 * (r >> 2) + 4 * (l >> 5);
        int rt = stripe * 32 + rl;
        int j = rt & 63;
        const float* vjr = Vjx + (size_t)(brow + j) * CD;
        float a1_ = 0.f, a2_ = 0.f;
        #pragma unroll
        for (int tt = 0; tt < 8; ++tt) {
            float m = acc[tt][r] + vix[tt] + vjr[cbase + tt * 32];
            acc[tt][r] = m;
            a1_ += m; a2_ = fmaf(m, m, a2_);
        }
        s1[r] = a1_; s2[r] = a2_;
    }
    #pragma unroll
    for (int off = 1; off < 32; off <<= 1) {
        #pragma unroll
        for (int r = 0; r < 16; ++r) {
            s1[r] += __shfl_xor(s1[r], off, 64);
            s2[r] += __shfl_xor(s2[r], off, 64);
        }
    }
    if ((l & 31) == 0) {
        #pragma unroll
        for (int r = 0; r < 16; ++r) {
            int rl = (r & 3) + 8 * (r >> 2) + 4 * (l >> 5);
            int rt = stripe * 32 + rl;
            sums[rt][H][0] = s1[r]; sums[rt][H][1] = s2[r];
        }
    }
    __syncthreads();   // also guarantees all waves finished K-loop tile reads

    // ---- env = edge + relu(LN(m)); write edge-out; tile <- w = exp(sigmoid(env)) ----
    #pragma unroll
    for (int r = 0; r < 16; ++r) {
        int rl = (r & 3) + 8 * (r >> 2) + 4 * (l >> 5);
        int rt = stripe * 32 + rl;
        float t1 = sums[rt][0][0] + sums[rt][1][0];
        float t2 = sums[rt][0][1] + sums[rt][1][1];
        float mean = t1 * (1.f / 512.f);
        float var  = t2 * (1.f / 512.f) - mean * mean;
        float rs   = rsqrtf(var + 1e-5f);
        int j = rt & 63;
        unsigned short* trow = tile + (size_t)rt * TPAD;
        float* erow = eout + ((size_t)biP * 64 + j) * CD;
        #pragma unroll
        for (int tt = 0; tt < 8; ++tt) {
            int c = cbase + tt * 32;
            float ln  = (acc[tt][r] - mean) * rs * gev[tt] + bev[tt];
            float env = bf2f(trow[c]) + fmaxf(ln, 0.f);
            erow[c] = env;
            float sg = 1.f / (1.f + __expf(-env));
            trow[c] = f2bf(__expf(sg));
        }
    }
    __syncthreads();

    // ---- softmax-over-j reduce + aggregate: thread t owns channel c=t ----
    {
        int c = t;
        #pragma unroll
        for (int pp = 0; pp < 2; ++pp) {
            const unsigned short* tp = tile + pp * 64 * TPAD;
            const float* uj = Ujx + (size_t)brow * CD + c;
            float den = 0.f, num = 0.f;
            #pragma unroll 8
            for (int j = 0; j < NNODE; ++j) {
                float wv = bf2f(tp[j * TPAD + c]);
                float uv = uj[(size_t)j * CD];
                den += wv; num = fmaf(wv, uv, num);
            }
            agg[(size_t)(bi0 + pp * 32) * CD + c] = num / (den * (float)NNODE);
        }
    }
}

// ---------------- x update: x = relu(res + LN(XU + agg)) ----------------
__global__ __launch_bounds__(256) void xupd_kernel(
    const float* __restrict__ res,
    const float* __restrict__ XU,
    const float* __restrict__ aggp,
    const float* __restrict__ gv, const float* __restrict__ bv,
    float* __restrict__ xout)
{
    int r = blockIdx.x * 4 + (threadIdx.x >> 6);
    int lane = threadIdx.x & 63;
    const float* xu = XU + (size_t)r * CD;
    const float* ag = aggp + (size_t)r * CD;
    float y[8]; float s1 = 0.f, s2 = 0.f;
    #pragma unroll
    for (int u = 0; u < 8; ++u) {
        int c = lane + u * 64;
        float v = xu[c] + ag[c];
        y[u] = v; s1 += v; s2 += v * v;
    }
    #pragma unroll
    for (int off = 32; off > 0; off >>= 1) {
        s1 += __shfl_xor(s1, off, 64);
        s2 += __shfl_xor(s2, off, 64);
    }
    float mean = s1 * (1.f / 512.f);
    float var  = s2 * (1.f / 512.f) - mean * mean;
    float rs   = rsqrtf(var + 1e-5f);
    const float* rr = res + (size_t)r * CD;
    float* xo = xout + (size_t)r * CD;
    #pragma unroll
    for (int u = 0; u < 8; ++u) {
        int c = lane + u * 64;
        float ln = (y[u] - mean) * rs * gv[c] + bv[c];
        xo[c] = fmaxf(rr[c] + ln, 0.f);
    }
}

extern "C" void kernel_launch(void* const* d_in, const int* in_sizes, int n_in,
                              void* d_out, int out_size, void* d_ws, size_t ws_size,
                              hipStream_t stream)
{
    const float* x    = (const float*)d_in[0];
    const float* edge = (const float*)d_in[1];
    const float* W[10];
    for (int i = 0; i < 10; ++i) W[i] = (const float*)d_in[2 + i];
    // 0 WA1, 1 WB1, 2 WE1, 3 WU1, 4 WV1, 5 WA2, 6 WB2, 7 WE2, 8 WU2, 9 WV2
    const float* ge1 = (const float*)d_in[12];
    const float* gv1 = (const float*)d_in[13];
    const float* ge2 = (const float*)d_in[14];
    const float* gv2 = (const float*)d_in[15];
    const float* be1 = (const float*)d_in[16];
    const float* bv1 = (const float*)d_in[17];
    const float* be2 = (const float*)d_in[18];
    const float* bv2 = (const float*)d_in[19];

    char* wsb = (char*)d_ws;
    unsigned short* P16 = (unsigned short*)wsb;                          // 8 x 512 KB
    unsigned short* P32 = (unsigned short*)(wsb + (size_t)4  * 1048576); // 2 x 512 KB
    float* Vix = (float*)(wsb + (size_t)5  * 1048576);
    float* Vjx = (float*)(wsb + (size_t)7  * 1048576);
    float* Ujx = (float*)(wsb + (size_t)9  * 1048576);
    float* XU  = (float*)(wsb + (size_t)11 * 1048576);
    float* agg = (float*)(wsb + (size_t)13 * 1048576);
    float* x1  = (float*)(wsb + (size_t)15 * 1048576);

    float* xout = (float*)d_out;
    float* eint = xout + (size_t)524288;

    // pack order widx: layer1 {WA1, WB1, WV1, WU1}, layer2 {WA2, WB2, WV2, WU2}
    pack16_k<<<dim3(16, 32, 8), 64, 0, stream>>>(
        W[0], W[1], W[4], W[3], W[5], W[6], W[9], W[8], P16);
    pack32_k<<<dim3(32, 16, 2), 64, 0, stream>>>(W[2], W[7], P32);

    // ---- layer 1 ----
    gemm4_mfma<<<dim3(64, 4), 256, 0, stream>>>(x, P16, Vix, Vjx, Ujx, XU);
    edge_mfma<<<512, 512, 0, stream>>>(edge, eint, Vix, Vjx, Ujx, P32, ge1, be1, agg);
    xupd_kernel<<<256, 256, 0, stream>>>(x, XU, agg, gv1, bv1, x1);
    // ---- layer 2 ----
    gemm4_mfma<<<dim3(64, 4), 256, 0, stream>>>(x1, P16 + (size_t)4 * 262144, Vix, Vjx, Ujx, XU);
    edge_mfma<<<512, 512, 0, stream>>>(eint, eint, Vix, Vjx, Ujx, P32 + 262144, ge2, be2, agg);
    xupd_kernel<<<256, 256, 0, stream>>>(x1, XU, agg, gv2, bv2, xout);
}

// Round 4
// 498.704 us; speedup vs baseline: 3.1510x; 1.1864x over previous
//
#include <hip/hip_runtime.h>
#include <math.h>

#define CD 512
#define NNODE 64
#define TPAD 520   // bf16 tile row stride: 1040 B, measured 0 bank conflicts in R3

typedef __attribute__((ext_vector_type(8)))  short bfrag8;   // 8 bf16 (4 VGPRs)
typedef __attribute__((ext_vector_type(8)))  short sv8;
typedef __attribute__((ext_vector_type(4)))  short sv4;
typedef __attribute__((ext_vector_type(16))) float f32x16;

__device__ __forceinline__ unsigned short f2bf(float f) {
    union { float f; unsigned u; } v; v.f = f;
    unsigned r = (v.u + 0x7fffu + ((v.u >> 16) & 1u)) >> 16;
    return (unsigned short)r;
}
__device__ __forceinline__ float bf2f(unsigned short u) {
    union { unsigned u; float f; } v; v.u = ((unsigned)u) << 16;
    return v.f;
}

// ---- pack 10 weights into 32x32x16 MFMA-B fragment order ----
// Bp[kt(32)][ct(16)][lane][i(8)] = W[c=ct*32+(l&31)][k=kt*16+(l>>5)*8+i]
__global__ void pack32_k(const float* __restrict__ W0, const float* __restrict__ W1,
                         const float* __restrict__ W2, const float* __restrict__ W3,
                         const float* __restrict__ W4, const float* __restrict__ W5,
                         const float* __restrict__ W6, const float* __restrict__ W7,
                         const float* __restrict__ W8, const float* __restrict__ W9,
                         unsigned short* __restrict__ out)
{
    const float* Ws[10] = {W0,W1,W2,W3,W4,W5,W6,W7,W8,W9};
    int kt = blockIdx.x, ct = blockIdx.y, wi = blockIdx.z, l = threadIdx.x;
    const float* W = Ws[wi];
    int c  = ct * 32 + (l & 31);
    int k0 = kt * 16 + (l >> 5) * 8;
    const float* src = W + (size_t)c * CD + k0;
    unsigned short o[8];
    #pragma unroll
    for (int i = 0; i < 8; ++i) o[i] = f2bf(src[i]);
    unsigned short* dst = out + (size_t)wi * 262144 + ((size_t)(kt * 16 + ct) * 64 + l) * 8;
    *(bfrag8*)dst = *(bfrag8*)o;
}

// ---- projection: O = A(1024x512) @ W.T, M=64 tile per block ----
__global__ __launch_bounds__(512, 4) void proj_mfma(
    const float* __restrict__ A, const unsigned short* __restrict__ Bp4,
    float* __restrict__ O0, float* __restrict__ O1,
    float* __restrict__ O2, float* __restrict__ O3)
{
    __shared__ unsigned short tile[64 * TPAD];
    const int rb = blockIdx.x * 64, widx = blockIdx.y;
    float* outs[4] = {O0,O1,O2,O3};
    float* out = outs[widx];
    const unsigned short* Bp = Bp4 + (size_t)widx * 262144;
    const int t = threadIdx.x, l = t & 63, w = t >> 6;
    const int stripe = w & 1, H = w >> 1;

    const float* src = A + (size_t)rb * CD;
    #pragma unroll 4
    for (int it = 0; it < 16; ++it) {
        int flat = it * 2048 + t * 4;
        float4 v4 = *(const float4*)(src + flat);
        int r = flat >> 9, c = flat & 511;
        sv4 pk; pk.x = (short)f2bf(v4.x); pk.y = (short)f2bf(v4.y);
        pk.z = (short)f2bf(v4.z); pk.w = (short)f2bf(v4.w);
        *(sv4*)(tile + r * TPAD + c) = pk;
    }
    __syncthreads();

    f32x16 acc[4] = {};
    const unsigned short* aptr = tile + (size_t)(stripe * 32 + (l & 31)) * TPAD + (l >> 5) * 8;
    const unsigned short* bptr = Bp + ((size_t)(H * 4) * 64 + l) * 8;

    bfrag8 a0, a1, b0[4], b1[4];
    a0 = *(const bfrag8*)aptr;
    #pragma unroll
    for (int tt = 0; tt < 4; ++tt) b0[tt] = *(const bfrag8*)(bptr + tt * 512);
    for (int k2 = 0; k2 < 16; ++k2) {
        int kt1 = 2 * k2 + 1;
        a1 = *(const bfrag8*)(aptr + kt1 * 16);
        #pragma unroll
        for (int tt = 0; tt < 4; ++tt) b1[tt] = *(const bfrag8*)(bptr + (size_t)kt1 * 8192 + tt * 512);
        #pragma unroll
        for (int tt = 0; tt < 4; ++tt)
            acc[tt] = __builtin_amdgcn_mfma_f32_32x32x16_bf16(a0, b0[tt], acc[tt], 0, 0, 0);
        int kt2 = (k2 == 15) ? 31 : (2 * k2 + 2);
        a0 = *(const bfrag8*)(aptr + kt2 * 16);
        #pragma unroll
        for (int tt = 0; tt < 4; ++tt) b0[tt] = *(const bfrag8*)(bptr + (size_t)kt2 * 8192 + tt * 512);
        #pragma unroll
        for (int tt = 0; tt < 4; ++tt)
            acc[tt] = __builtin_amdgcn_mfma_f32_32x32x16_bf16(a1, b1[tt], acc[tt], 0, 0, 0);
    }
    // C layout 32x32: col = lane&31, row = (reg&3)+8*(reg>>2)+4*(lane>>5)
    const int cbase = H * 128 + (l & 31);
    #pragma unroll
    for (int r = 0; r < 16; ++r) {
        int rl = (r & 3) + 8 * (r >> 2) + 4 * (l >> 5);
        int row = rb + stripe * 32 + rl;
        #pragma unroll
        for (int tt = 0; tt < 4; ++tt)
            out[(size_t)row * CD + cbase + tt * 32] = acc[tt][r];
    }
}

// ---- fused edge kernel: one (b,i) pair per block, M=64 ----
template<bool INBF, bool OUTBF>
__global__ __launch_bounds__(512, 4) void edge_mfma(
    const void* __restrict__ einv, void* __restrict__ eoutv,
    const float* __restrict__ Vix, const float* __restrict__ Vjx,
    const float* __restrict__ Ujx, const unsigned short* __restrict__ Bp,
    const float* __restrict__ ge, const float* __restrict__ be,
    float* __restrict__ agg)
{
    __shared__ unsigned short tile[64 * TPAD];   // 66.6 KB
    __shared__ float sums[64][4][2];             // [row][H-quarter][s1,s2]

    const int bi = blockIdx.x;                   // b*64 + i
    const int brow = bi & ~63;                   // b*64
    const int t = threadIdx.x, l = t & 63, w = t >> 6;
    const int stripe = w & 1, H = w >> 1;        // 2 row-stripes x 4 col-quarters

    // ---- stage edge pair -> bf16 LDS ----
    if (INBF) {
        const unsigned short* src = (const unsigned short*)einv + (size_t)bi * 65536;
        #pragma unroll 4
        for (int it = 0; it < 8; ++it) {
            int flat = it * 4096 + t * 8;
            int r = flat >> 9, c = flat & 511;
            *(sv8*)(tile + r * TPAD + c) = *(const sv8*)(src + flat);
        }
    } else {
        const float* src = (const float*)einv + (size_t)bi * 32768;
        #pragma unroll 4
        for (int it = 0; it < 16; ++it) {
            int flat = it * 2048 + t * 4;
            float4 v4 = *(const float4*)(src + flat);
            int r = flat >> 9, c = flat & 511;
            sv4 pk; pk.x = (short)f2bf(v4.x); pk.y = (short)f2bf(v4.y);
            pk.z = (short)f2bf(v4.z); pk.w = (short)f2bf(v4.w);
            *(sv4*)(tile + r * TPAD + c) = pk;
        }
    }
    __syncthreads();

    // ---- K-loop: 32 steps of K=16, zero barriers, B streamed from L2 ----
    f32x16 acc[4] = {};
    const unsigned short* aptr = tile + (size_t)(stripe * 32 + (l & 31)) * TPAD + (l >> 5) * 8;
    const unsigned short* bptr = Bp + ((size_t)(H * 4) * 64 + l) * 8;

    bfrag8 a0, a1, b0[4], b1[4];
    a0 = *(const bfrag8*)aptr;
    #pragma unroll
    for (int tt = 0; tt < 4; ++tt) b0[tt] = *(const bfrag8*)(bptr + tt * 512);
    for (int k2 = 0; k2 < 16; ++k2) {
        int kt1 = 2 * k2 + 1;
        a1 = *(const bfrag8*)(aptr + kt1 * 16);
        #pragma unroll
        for (int tt = 0; tt < 4; ++tt) b1[tt] = *(const bfrag8*)(bptr + (size_t)kt1 * 8192 + tt * 512);
        #pragma unroll
        for (int tt = 0; tt < 4; ++tt)
            acc[tt] = __builtin_amdgcn_mfma_f32_32x32x16_bf16(a0, b0[tt], acc[tt], 0, 0, 0);
        int kt2 = (k2 == 15) ? 31 : (2 * k2 + 2);
        a0 = *(const bfrag8*)(aptr + kt2 * 16);
        #pragma unroll
        for (int tt = 0; tt < 4; ++tt) b0[tt] = *(const bfrag8*)(bptr + (size_t)kt2 * 8192 + tt * 512);
        #pragma unroll
        for (int tt = 0; tt < 4; ++tt)
            acc[tt] = __builtin_amdgcn_mfma_f32_32x32x16_bf16(a1, b1[tt], acc[tt], 0, 0, 0);
    }

    // ---- epilogue: m = acc + vix + vjx; LN partial stats over 128 cols ----
    const int cbase = H * 128 + (l & 31);
    float vix[4], gev[4], bev[4];
    #pragma unroll
    for (int tt = 0; tt < 4; ++tt) {
        int c = cbase + tt * 32;
        vix[tt] = Vix[(size_t)bi * CD + c];
        gev[tt] = ge[c]; bev[tt] = be[c];
    }
    float s1[16], s2[16];
    #pragma unroll
    for (int r = 0; r < 16; ++r) {
        int rl = (r & 3) + 8 * (r >> 2) + 4 * (l >> 5);
        int rt = stripe * 32 + rl;               // row = j in [0,64)
        const float* vjr = Vjx + (size_t)(brow + rt) * CD;
        float a1_ = 0.f, a2_ = 0.f;
        #pragma unroll
        for (int tt = 0; tt < 4; ++tt) {
            float m = acc[tt][r] + vix[tt] + vjr[cbase + tt * 32];
            acc[tt][r] = m;
            a1_ += m; a2_ = fmaf(m, m, a2_);
        }
        s1[r] = a1_; s2[r] = a2_;
    }
    #pragma unroll
    for (int off = 1; off < 32; off <<= 1) {
        #pragma unroll
        for (int r = 0; r < 16; ++r) {
            s1[r] += __shfl_xor(s1[r], off, 64);
            s2[r] += __shfl_xor(s2[r], off, 64);
        }
    }
    if ((l & 31) == 0) {
        #pragma unroll
        for (int r = 0; r < 16; ++r) {
            int rl = (r & 3) + 8 * (r >> 2) + 4 * (l >> 5);
            int rt = stripe * 32 + rl;
            sums[rt][H][0] = s1[r]; sums[rt][H][1] = s2[r];
        }
    }
    __syncthreads();

    // ---- env = edge + relu(LN(m)); write; tile <- exp(sigmoid(env)) ----
    #pragma unroll
    for (int r = 0; r < 16; ++r) {
        int rl = (r & 3) + 8 * (r >> 2) + 4 * (l >> 5);
        int rt = stripe * 32 + rl;
        float t1 = sums[rt][0][0] + sums[rt][1][0] + sums[rt][2][0] + sums[rt][3][0];
        float t2 = sums[rt][0][1] + sums[rt][1][1] + sums[rt][2][1] + sums[rt][3][1];
        float mean = t1 * (1.f / 512.f);
        float var  = t2 * (1.f / 512.f) - mean * mean;
        float rs   = rsqrtf(var + 1e-5f);
        unsigned short* trow = tile + (size_t)rt * TPAD;
        #pragma unroll
        for (int tt = 0; tt < 4; ++tt) {
            int c = cbase + tt * 32;
            float ln  = (acc[tt][r] - mean) * rs * gev[tt] + bev[tt];
            float env = bf2f(trow[c]) + fmaxf(ln, 0.f);
            if (OUTBF) ((unsigned short*)eoutv)[(size_t)bi * 65536 + rt * 512 + c] = f2bf(env);
            else       ((float*)eoutv)[(size_t)bi * 32768 + rt * 512 + c] = env;
            float sg = 1.f / (1.f + __expf(-env));
            trow[c] = f2bf(__expf(sg));
        }
    }
    __syncthreads();

    // ---- softmax-over-j reduce + aggregate: thread t owns channel c=t ----
    {
        int c = t;
        const float* uj = Ujx + (size_t)brow * CD + c;
        float den = 0.f, num = 0.f;
        #pragma unroll 8
        for (int j = 0; j < NNODE; ++j) {
            float wv = bf2f(tile[j * TPAD + c]);
            float uv = uj[(size_t)j * CD];
            den += wv; num = fmaf(wv, uv, num);
        }
        agg[(size_t)bi * CD + c] = num / (den * (float)NNODE);
    }
}

// ---- x update: x = relu(res + LN(XU + agg)) ----
__global__ __launch_bounds__(256) void xupd_kernel(
    const float* __restrict__ res,
    const float* __restrict__ XU,
    const float* __restrict__ aggp,
    const float* __restrict__ gv, const float* __restrict__ bv,
    float* __restrict__ xout)
{
    int r = blockIdx.x * 4 + (threadIdx.x >> 6);
    int lane = threadIdx.x & 63;
    const float* xu = XU + (size_t)r * CD;
    const float* ag = aggp + (size_t)r * CD;
    float y[8]; float s1 = 0.f, s2 = 0.f;
    #pragma unroll
    for (int u = 0; u < 8; ++u) {
        int c = lane + u * 64;
        float v = xu[c] + ag[c];
        y[u] = v; s1 += v; s2 += v * v;
    }
    #pragma unroll
    for (int off = 32; off > 0; off >>= 1) {
        s1 += __shfl_xor(s1, off, 64);
        s2 += __shfl_xor(s2, off, 64);
    }
    float mean = s1 * (1.f / 512.f);
    float var  = s2 * (1.f / 512.f) - mean * mean;
    float rs   = rsqrtf(var + 1e-5f);
    const float* rr = res + (size_t)r * CD;
    float* xo = xout + (size_t)r * CD;
    #pragma unroll
    for (int u = 0; u < 8; ++u) {
        int c = lane + u * 64;
        float ln = (y[u] - mean) * rs * gv[c] + bv[c];
        xo[c] = fmaxf(rr[c] + ln, 0.f);
    }
}

extern "C" void kernel_launch(void* const* d_in, const int* in_sizes, int n_in,
                              void* d_out, int out_size, void* d_ws, size_t ws_size,
                              hipStream_t stream)
{
    const float* x    = (const float*)d_in[0];
    const float* edge = (const float*)d_in[1];
    const float* W[10];
    for (int i = 0; i < 10; ++i) W[i] = (const float*)d_in[2 + i];
    // 0 WA1, 1 WB1, 2 WE1, 3 WU1, 4 WV1, 5 WA2, 6 WB2, 7 WE2, 8 WU2, 9 WV2
    const float* ge1 = (const float*)d_in[12];
    const float* gv1 = (const float*)d_in[13];
    const float* ge2 = (const float*)d_in[14];
    const float* gv2 = (const float*)d_in[15];
    const float* be1 = (const float*)d_in[16];
    const float* bv1 = (const float*)d_in[17];
    const float* be2 = (const float*)d_in[18];
    const float* bv2 = (const float*)d_in[19];

    char* wsb = (char*)d_ws;
    unsigned short* P32 = (unsigned short*)wsb;               // 10 x 512 KB = 5 MB
    float* Vix = (float*)(wsb + (size_t)6  * 1048576);
    float* Vjx = (float*)(wsb + (size_t)8  * 1048576);
    float* Ujx = (float*)(wsb + (size_t)10 * 1048576);
    float* XU  = (float*)(wsb + (size_t)12 * 1048576);
    float* agg = (float*)(wsb + (size_t)14 * 1048576);
    float* x1  = (float*)(wsb + (size_t)16 * 1048576);

    float* xout  = (float*)d_out;
    float* eintF = xout + (size_t)524288;     // edge region (bf16 lives in slot's first half)

    // pack order: 0 WA1, 1 WB1, 2 WV1, 3 WU1, 4 WA2, 5 WB2, 6 WV2, 7 WU2, 8 WE1, 9 WE2
    pack32_k<<<dim3(32, 16, 10), 64, 0, stream>>>(
        W[0], W[1], W[4], W[3], W[5], W[6], W[9], W[8], W[2], W[7], P32);

#define PW(i) (P32 + (size_t)(i) * 262144)
    // ---- layer 1 ----
    proj_mfma<<<dim3(16, 4), 512, 0, stream>>>(x, PW(0), Vix, Vjx, Ujx, XU);
    edge_mfma<false, true><<<1024, 512, 0, stream>>>(edge, eintF, Vix, Vjx, Ujx,
                                                     PW(8), ge1, be1, agg);
    xupd_kernel<<<256, 256, 0, stream>>>(x, XU, agg, gv1, bv1, x1);
    // ---- layer 2 ----
    proj_mfma<<<dim3(16, 4), 512, 0, stream>>>(x1, PW(4), Vix, Vjx, Ujx, XU);
    edge_mfma<true, false><<<1024, 512, 0, stream>>>(eintF, eintF, Vix, Vjx, Ujx,
                                                     PW(9), ge2, be2, agg);
    xupd_kernel<<<256, 256, 0, stream>>>(x1, XU, agg, gv2, bv2, xout);
#undef PW
}